// Round 7
// baseline (954.807 us; speedup 1.0000x reference)
//
#include <hip/hip_runtime.h>
#include <cstdint>
#include <cstddef>

#define MROWS 24000
#define NCOLS 1024
#define KDIM  768
#define MT 188          // ceil(24000/128) m-tiles (padded to 24064 rows)
#define KT 48           // 768/16 k-tiles
#define NT 4            // 1024/256 n-tiles

typedef _Float16 f16x8  __attribute__((ext_vector_type(8)));
typedef float    f32x16 __attribute__((ext_vector_type(16)));

typedef __attribute__((address_space(1))) void as1_void;
typedef __attribute__((address_space(3))) void as3_void;

// ---- workspace layout (bytes) ----
#define A_BYTES   (188ull*48*8192)            // 73,924,608
#define B_OFF     A_BYTES
#define B_BYTES   (4ull*48*16384)             // 3,145,728
#define CH_OFF    (A_BYTES + B_BYTES)         // 77,070,336
#define PART_OFF  (CH_OFF + 4096)             // 77,074,432
#define WS_NEED   (PART_OFF + 24064ull*4*8)   // 77,844,480

// ---------------- conv A: embed -> tiled fp16 hi/lo ----------------
__global__ void k_tile_A(const float* __restrict__ E, _Float16* __restrict__ Aw) {
  int bid = blockIdx.x;            // mt*48 + kt
  int mt = bid / 48, kt = bid % 48;
  int t = threadIdx.x;             // 256
  int r = t >> 1, p = t & 1;
  int row = mt * 128 + r;
  __shared__ _Float16 lh[2][128][8];
  __shared__ _Float16 ll[2][128][8];
  float x[8];
  if (row < MROWS) {
    const float4* s4 = (const float4*)(E + (size_t)row * KDIM + kt * 16 + p * 8);
    float4 v0 = s4[0], v1 = s4[1];
    x[0]=v0.x; x[1]=v0.y; x[2]=v0.z; x[3]=v0.w; x[4]=v1.x; x[5]=v1.y; x[6]=v1.z; x[7]=v1.w;
  } else {
#pragma unroll
    for (int e = 0; e < 8; ++e) x[e] = 0.f;
  }
#pragma unroll
  for (int e = 0; e < 8; ++e) {
    _Float16 h = (_Float16)x[e];
    lh[p][r][e] = h;
    ll[p][r][e] = (_Float16)(x[e] - (float)h);
  }
  __syncthreads();
  const uint4* sh = (const uint4*)&lh[0][0][0];
  const uint4* sl = (const uint4*)&ll[0][0][0];
  uint4* dst = (uint4*)(Aw + (size_t)bid * 4096);   // 8192 B per tile
  dst[t]       = sh[t];    // h region: 256 chunks
  dst[256 + t] = sl[t];    // l region
}

// ---------------- conv B: centers -> tiled fp16 hi/lo ----------------
__global__ void k_tile_B(const float* __restrict__ C, _Float16* __restrict__ Bw) {
  int bid = blockIdx.x;            // nt*48 + kt
  int nt = bid / 48, kt = bid % 48;
  int t = threadIdx.x;             // 512
  int c = t >> 1, p = t & 1;
  __shared__ _Float16 lh[2][256][8];
  __shared__ _Float16 ll[2][256][8];
  const float4* s4 = (const float4*)(C + (size_t)(nt * 256 + c) * KDIM + kt * 16 + p * 8);
  float4 v0 = s4[0], v1 = s4[1];
  float x[8] = {v0.x, v0.y, v0.z, v0.w, v1.x, v1.y, v1.z, v1.w};
#pragma unroll
  for (int e = 0; e < 8; ++e) {
    _Float16 h = (_Float16)x[e];
    lh[p][c][e] = h;
    ll[p][c][e] = (_Float16)(x[e] - (float)h);
  }
  __syncthreads();
  const uint4* sh = (const uint4*)&lh[0][0][0];
  const uint4* sl = (const uint4*)&ll[0][0][0];
  uint4* dst = (uint4*)(Bw + (size_t)bid * 8192);   // 16384 B per tile
  dst[t]       = sh[t];    // h region: 512 chunks
  dst[512 + t] = sl[t];    // l region
}

// ---------------- 0.5*||c||^2 ----------------
__global__ void k_chalf(const float* __restrict__ C, float* __restrict__ ch) {
  int c = blockIdx.x, t = threadIdx.x;   // 256
  const float* src = C + (size_t)c * KDIM;
  float sq = 0.f;
#pragma unroll
  for (int i = 0; i < 3; ++i) {
    float x = src[t + i * 256];
    sq = fmaf(x, x, sq);
  }
#pragma unroll
  for (int m = 1; m < 64; m <<= 1) sq += __shfl_xor(sq, m, 64);
  __shared__ float part[4];
  if ((t & 63) == 0) part[t >> 6] = sq;
  __syncthreads();
  if (t == 0) ch[c] = 0.5f * ((part[0] + part[1]) + (part[2] + part[3]));
}

// ---------------- fused GEMM (32x32x16 f16, hi/lo x3) + per-tile argmax ----------------
// Round-0 verified structure, with LDS cut 53248 -> 49152: the 4KB argmax
// reduction arrays now ALIAS the staging buffers (dead after the K-loop's
// final __syncthreads). 160KB / 49152 = 3 blocks/CU resident (was 2):
// (a) grid 752 <= 768 slots -> single dispatch generation (tail 0.73 -> ~0.93),
// (b) 3 independent block streams per CU interleave their latency stalls.
// launch_bounds(512,6) pins VGPR <= 85 (uses ~52).
__global__ __launch_bounds__(512, 6) void k_gemm(
    const _Float16* __restrict__ Aw, const _Float16* __restrict__ Bw,
    const float* __restrict__ ch, uint2* __restrict__ part) {
  __shared__ __align__(16) char smem[2][24576];   // [A-h 4K][A-l 4K][B-h 8K][B-l 8K]
  // epilogue reduction arrays alias smem[0] (staging dead after K-loop)
  float (&red_v)[4][128] = *reinterpret_cast<float (*)[4][128]>(&smem[0][0]);
  int   (&red_i)[4][128] = *reinterpret_cast<int   (*)[4][128]>(&smem[0][2048]);

  int bid0 = blockIdx.x;                      // 0..751
  int swz = (bid0 & 7) * 94 + (bid0 >> 3);    // 752 = 8*94, bijective; nt-contig per XCD
  int nt = swz / MT, mt = swz % MT;

  const int tid = threadIdx.x, lane = tid & 63, wid = tid >> 6;
  const int wm = wid >> 2, wn = wid & 3;      // 2 x 4 wave grid, wave tile 64x64
  const int lo5 = lane & 31, p = lane >> 5;

  const char* Ab = (const char*)Aw + (size_t)mt * (48 * 8192);
  const char* Bb = (const char*)Bw + (size_t)nt * (48 * 16384);

  auto stage = [&](int buf, int kt) {
    char* sb = smem[buf];
    const char* ga = Ab + kt * 8192;
    const char* gb = Bb + kt * 16384;
    __builtin_amdgcn_global_load_lds((as1_void*)(ga + tid * 16),        (as3_void*)(sb + tid * 16),         16, 0, 0);
    __builtin_amdgcn_global_load_lds((as1_void*)(gb + tid * 16),        (as3_void*)(sb + 8192 + tid * 16),  16, 0, 0);
    __builtin_amdgcn_global_load_lds((as1_void*)(gb + 8192 + tid * 16), (as3_void*)(sb + 16384 + tid * 16), 16, 0, 0);
  };

  f32x16 acc[2][2] = {};

  stage(0, 0);
  __syncthreads();

  int buf = 0;
  for (int kt = 0; kt < KT; ++kt) {
    if (kt + 1 < KT) stage(buf ^ 1, kt + 1);

    const char* sb = smem[buf];
    f16x8 ah[2], al[2], bh[2], bl[2];
#pragma unroll
    for (int mi = 0; mi < 2; ++mi) {
      int off = p * 2048 + (wm * 64 + mi * 32 + lo5) * 16;
      ah[mi] = *(const f16x8*)(sb + off);
      al[mi] = *(const f16x8*)(sb + 4096 + off);
    }
#pragma unroll
    for (int ni = 0; ni < 2; ++ni) {
      int off = p * 4096 + (wn * 64 + ni * 32 + lo5) * 16;
      bh[ni] = *(const f16x8*)(sb + 8192 + off);
      bl[ni] = *(const f16x8*)(sb + 16384 + off);
    }
#pragma unroll
    for (int mi = 0; mi < 2; ++mi)
#pragma unroll
      for (int ni = 0; ni < 2; ++ni) {
        acc[mi][ni] = __builtin_amdgcn_mfma_f32_32x32x16_f16(ah[mi], bh[ni], acc[mi][ni], 0, 0, 0);
        acc[mi][ni] = __builtin_amdgcn_mfma_f32_32x32x16_f16(ah[mi], bl[ni], acc[mi][ni], 0, 0, 0);
        acc[mi][ni] = __builtin_amdgcn_mfma_f32_32x32x16_f16(al[mi], bh[ni], acc[mi][ni], 0, 0, 0);
      }
    __syncthreads();   // drains vmcnt(0): next tile staged; all waves done reading buf
    buf ^= 1;
  }

  // ---- epilogue: per-row argmax over this wave's 64 cols, then merge across wn ----
  // (K-loop ended with __syncthreads: all waves past their smem reads; red_*
  //  aliasing smem[0] is now safe to write.)
  int c0 = nt * 256 + wn * 64 + lo5;
  int c1 = c0 + 32;
  float ch0 = ch[c0];
  float ch1 = ch[c1];
#pragma unroll
  for (int mi = 0; mi < 2; ++mi)
#pragma unroll
    for (int q = 0; q < 16; ++q) {
      float s0 = acc[mi][0][q] - ch0;
      float s1 = acc[mi][1][q] - ch1;
      float v = s0; int ix = c0;
      if (s1 > v) { v = s1; ix = c1; }   // c1 > c0: strict > keeps first index on ties
#pragma unroll
      for (int m = 1; m <= 16; m <<= 1) {
        float ov = __shfl_xor(v, m, 64);
        int   oi = __shfl_xor(ix, m, 64);
        if (ov > v || (ov == v && oi < ix)) { v = ov; ix = oi; }
      }
      if (lo5 == 0) {
        int rr = (q & 3) + ((q >> 2) << 3) + (p << 2);   // C/D row within 32x32 tile
        int rloc = wm * 64 + mi * 32 + rr;               // 0..127, unique per (wm,mi,q,p)
        red_v[wn][rloc] = v;
        red_i[wn][rloc] = ix;
      }
    }
  __syncthreads();
  if (tid < 128) {
    float v = red_v[0][tid];
    int ix = red_i[0][tid];
#pragma unroll
    for (int w = 1; w < 4; ++w) {       // wn ascending => col ascending; strict > keeps first
      float ov = red_v[w][tid];
      int oi = red_i[w][tid];
      if (ov > v) { v = ov; ix = oi; }
    }
    int rowg = mt * 128 + tid;
    part[rowg * 4 + nt] = uint2{ __float_as_uint(v), (unsigned)ix };
  }
}

// ---------------- merge the 4 per-ntile candidates ----------------
__global__ void k_merge(const uint2* __restrict__ part, int* __restrict__ out) {
  int r = blockIdx.x * 256 + threadIdx.x;
  if (r >= MROWS) return;
  uint2 b0 = part[r * 4];
  float bvv = __uint_as_float(b0.x);
  int bii = (int)b0.y;
#pragma unroll
  for (int j = 1; j < 4; ++j) {
    uint2 pj = part[r * 4 + j];
    float v = __uint_as_float(pj.x);
    if (v > bvv) { bvv = v; bii = (int)pj.y; }   // nt ascending => idx ascending; strict >
  }
  out[r] = bii;
}

// ---------------- fallback (ws too small): fp32 wave-per-row ----------------
__global__ void k_naive(const float* __restrict__ E, const float* __restrict__ C,
                        int* __restrict__ out) {
  int row = blockIdx.x * 4 + (threadIdx.x >> 6);
  int lane = threadIdx.x & 63;
  const float* e = E + (size_t)row * KDIM;
  float bvv = -3.4e38f;
  int bii = 0;
  for (int c = 0; c < NCOLS; ++c) {
    const float* cc = C + (size_t)c * KDIM;
    float dot = 0.f, csq = 0.f;
    for (int d = lane; d < KDIM; d += 64) {
      float cv = cc[d];
      dot = fmaf(e[d], cv, dot);
      csq = fmaf(cv, cv, csq);
    }
#pragma unroll
    for (int m = 1; m < 64; m <<= 1) {
      dot += __shfl_xor(dot, m, 64);
      csq += __shfl_xor(csq, m, 64);
    }
    float s = dot - 0.5f * csq;
    if (s > bvv) { bvv = s; bii = c; }
  }
  if (lane == 0) out[row] = bii;
}

extern "C" void kernel_launch(void* const* d_in, const int* in_sizes, int n_in,
                              void* d_out, int out_size, void* d_ws, size_t ws_size,
                              hipStream_t stream) {
  const float* embed   = (const float*)d_in[0];
  const float* centers = (const float*)d_in[1];
  int* out = (int*)d_out;

  if (ws_size >= WS_NEED) {
    char* w = (char*)d_ws;
    _Float16* Aw = (_Float16*)w;
    _Float16* Bw = (_Float16*)(w + B_OFF);
    float*    ch = (float*)(w + CH_OFF);
    uint2*  partb = (uint2*)(w + PART_OFF);
    k_tile_A<<<188 * 48, 256, 0, stream>>>(embed, Aw);
    k_tile_B<<<4 * 48, 512, 0, stream>>>(centers, Bw);
    k_chalf<<<1024, 256, 0, stream>>>(centers, ch);
    k_gemm<<<752, 512, 0, stream>>>(Aw, Bw, ch, partb);
    k_merge<<<94, 256, 0, stream>>>(partb, out);
  } else {
    k_naive<<<6000, 256, 0, stream>>>(embed, centers, out);
  }
}

// Round 8
// 218.061 us; speedup vs baseline: 4.3786x; 4.3786x over previous
//
#include <hip/hip_runtime.h>
#include <cstdint>
#include <cstddef>

#define MROWS 24000
#define NCOLS 1024
#define KDIM  768
#define MT 188          // ceil(24000/128) A row-granules of 128
#define MT2 94          // 256-row gemm tiles
#define KT 48           // 768/16 k-granules
#define NK 24           // 768/32 gemm K-steps

typedef _Float16 f16x8  __attribute__((ext_vector_type(8)));
typedef float    f32x16 __attribute__((ext_vector_type(16)));

typedef __attribute__((address_space(1))) void as1_void;
typedef __attribute__((address_space(3))) void as3_void;

// ---- workspace layout (bytes) ----
#define A_BYTES   (188ull*48*8192)            // 73,924,608
#define B_OFF     A_BYTES
#define B_BYTES   (4ull*48*16384)             // 3,145,728
#define CH_OFF    (A_BYTES + B_BYTES)         // 77,070,336
#define PART_OFF  (CH_OFF + 4096)             // 77,074,432
#define WS_NEED   (PART_OFF + 24064ull*4*8)   // 77,844,480

// ---------------- conv A: embed -> tiled fp16 hi/lo ----------------
__global__ void k_tile_A(const float* __restrict__ E, _Float16* __restrict__ Aw) {
  int bid = blockIdx.x;            // mt*48 + kt
  int mt = bid / 48, kt = bid % 48;
  int t = threadIdx.x;             // 256
  int r = t >> 1, p = t & 1;
  int row = mt * 128 + r;
  __shared__ _Float16 lh[2][128][8];
  __shared__ _Float16 ll[2][128][8];
  float x[8];
  if (row < MROWS) {
    const float4* s4 = (const float4*)(E + (size_t)row * KDIM + kt * 16 + p * 8);
    float4 v0 = s4[0], v1 = s4[1];
    x[0]=v0.x; x[1]=v0.y; x[2]=v0.z; x[3]=v0.w; x[4]=v1.x; x[5]=v1.y; x[6]=v1.z; x[7]=v1.w;
  } else {
#pragma unroll
    for (int e = 0; e < 8; ++e) x[e] = 0.f;
  }
#pragma unroll
  for (int e = 0; e < 8; ++e) {
    _Float16 h = (_Float16)x[e];
    lh[p][r][e] = h;
    ll[p][r][e] = (_Float16)(x[e] - (float)h);
  }
  __syncthreads();
  const uint4* sh = (const uint4*)&lh[0][0][0];
  const uint4* sl = (const uint4*)&ll[0][0][0];
  uint4* dst = (uint4*)(Aw + (size_t)bid * 4096);   // 8192 B per granule
  dst[t]       = sh[t];    // h region: 256 chunks
  dst[256 + t] = sl[t];    // l region
}

// ---------------- conv B: centers -> tiled fp16 hi/lo ----------------
__global__ void k_tile_B(const float* __restrict__ C, _Float16* __restrict__ Bw) {
  int bid = blockIdx.x;            // nt*48 + kt   (nt in 256-col units)
  int nt = bid / 48, kt = bid % 48;
  int t = threadIdx.x;             // 512
  int c = t >> 1, p = t & 1;
  __shared__ _Float16 lh[2][256][8];
  __shared__ _Float16 ll[2][256][8];
  const float4* s4 = (const float4*)(C + (size_t)(nt * 256 + c) * KDIM + kt * 16 + p * 8);
  float4 v0 = s4[0], v1 = s4[1];
  float x[8] = {v0.x, v0.y, v0.z, v0.w, v1.x, v1.y, v1.z, v1.w};
#pragma unroll
  for (int e = 0; e < 8; ++e) {
    _Float16 h = (_Float16)x[e];
    lh[p][c][e] = h;
    ll[p][c][e] = (_Float16)(x[e] - (float)h);
  }
  __syncthreads();
  const uint4* sh = (const uint4*)&lh[0][0][0];
  const uint4* sl = (const uint4*)&ll[0][0][0];
  uint4* dst = (uint4*)(Bw + (size_t)bid * 8192);   // 16384 B per granule
  dst[t]       = sh[t];    // h region: 512 chunks
  dst[512 + t] = sl[t];    // l region
}

// ---------------- 0.5*||c||^2 ----------------
__global__ void k_chalf(const float* __restrict__ C, float* __restrict__ ch) {
  int c = blockIdx.x, t = threadIdx.x;   // 256
  const float* src = C + (size_t)c * KDIM;
  float sq = 0.f;
#pragma unroll
  for (int i = 0; i < 3; ++i) {
    float x = src[t + i * 256];
    sq = fmaf(x, x, sq);
  }
#pragma unroll
  for (int m = 1; m < 64; m <<= 1) sq += __shfl_xor(sq, m, 64);
  __shared__ float part[4];
  if ((t & 63) == 0) part[t >> 6] = sq;
  __syncthreads();
  if (t == 0) ch[c] = 0.5f * ((part[0] + part[1]) + (part[2] + part[3]));
}

#define MFMA16(a, b, c) __builtin_amdgcn_mfma_f32_32x32x16_f16((a), (b), (c), 0, 0, 0)

// ---------------- fused GEMM: 256x256 tile, 8-phase fine interleave, BK=32 ----------------
// m201-template port. 8 waves (2x4), wave tile 128x64, acc[4][2] (128 regs ->
// 2 waves/SIMD by the 512-reg/SIMD pool). Double-buffered 64KB LDS sets
// {A 4x8K granules | B 2x16K granules}; 8 stage insts per K-step issued one
// per phase; uniform s_waitcnt vmcnt(4) at each half-step entry (granule
// always issued ~4 phases = ~700cyc before use; never drains to 0 until the
// final half). Per phase: ds_reads (A read once per mi-pair, B kept live
// across phases) -> 1 stage -> raw s_barrier -> setprio(1) -> 6 MFMA ->
// setprio(0) -> barrier. Per-acc chain: hh, h*bl, al*bh, kt ascending ->
// bitwise-identical scores to the verified baseline.
__global__ __launch_bounds__(512, 2) void k_gemm(
    const _Float16* __restrict__ Aw, const _Float16* __restrict__ Bw,
    const float* __restrict__ ch, uint2* __restrict__ part) {
  __shared__ __align__(16) char smem[2][65536];   // [A: (t*2+g)*8K x4][B @32768: t*16K x2]
  __shared__ float red_v[4][256];
  __shared__ int   red_i[4][256];

  const int bid0 = blockIdx.x;                    // 0..375
  const int swz = (bid0 & 7) * 47 + (bid0 >> 3);  // 376 = 8*47, bijective XCD swizzle
  const int nt = swz / MT2, mt2 = swz % MT2;

  const int tid = threadIdx.x, lane = tid & 63, wid = tid >> 6;  // 8 waves
  const int wm = wid >> 2, wn = wid & 3;          // 2x4 grid, wave tile 128x64
  const int lo5 = lane & 31, p = lane >> 5;

  const char* Ab = (const char*)Aw + (size_t)(mt2 * 2) * (48 * 8192);
  const char* Bb = (const char*)Bw + (size_t)nt * (48 * 16384);

  auto stA = [&](char* wb, int k16, int t, int g) {   // one 8KB granule
    __builtin_amdgcn_global_load_lds(
        (as1_void*)(Ab + ((size_t)g * 48 + k16) * 8192 + tid * 16),
        (as3_void*)(wb + (t * 2 + g) * 8192 + tid * 16), 16, 0, 0);
  };
  auto stB = [&](char* wb, int k16, int t, int h) {   // half of a 16KB granule
    __builtin_amdgcn_global_load_lds(
        (as1_void*)(Bb + (size_t)k16 * 16384 + h * 8192 + tid * 16),
        (as3_void*)(wb + 32768 + t * 16384 + h * 8192 + tid * 16), 16, 0, 0);
  };

  f32x16 acc[4][2] = {};

  const int offAr = p * 2048 + lo5 * 16;                       // + mi*512; plane +4096
  const int offBr = 32768 + p * 4096 + (wn * 64 + lo5) * 16;   // + ni*512; plane +8192

  // prologue: stage granule-sets (0,0) and (0,1) -> 8 loads in flight
  stA(smem[0], 0, 0, 0); stA(smem[0], 0, 0, 1); stB(smem[0], 0, 0, 0); stB(smem[0], 0, 0, 1);
  stA(smem[0], 1, 1, 0); stA(smem[0], 1, 1, 1); stB(smem[0], 1, 1, 0); stB(smem[0], 1, 1, 1);

#pragma unroll 1
  for (int j = 0; j < NK; ++j) {
    const char* rb = smem[j & 1];
    char* wb = smem[(j + 1) & 1];
    const bool pre = (j + 1 < NK);
    const int nk0 = 2 * (j + 1);
#pragma unroll
    for (int t = 0; t < 2; ++t) {
      // granule (j,t) landed for this wave; (j,t+1)/(j+1,*) stay in flight
      if (t == 0 || pre) asm volatile("s_waitcnt vmcnt(4)" ::: "memory");
      else               asm volatile("s_waitcnt vmcnt(0)" ::: "memory");
      __builtin_amdgcn_s_barrier();

      const char* at = rb + (t * 2 + wm) * 8192;
      const char* bt = rb + t * 16384;
      f16x8 ah0, ah1, al0, al1, bh0, bl0, bh1, bl1;

      // ---- phase 0: A mp0 + B ni0; stage A g0 ----
      ah0 = *(const f16x8*)(at + offAr);
      ah1 = *(const f16x8*)(at + offAr + 512);
      al0 = *(const f16x8*)(at + 4096 + offAr);
      al1 = *(const f16x8*)(at + 4096 + offAr + 512);
      bh0 = *(const f16x8*)(bt + offBr);
      bl0 = *(const f16x8*)(bt + 8192 + offBr);
      if (pre) stA(wb, nk0 + t, t, 0);
      __builtin_amdgcn_s_barrier();
      __builtin_amdgcn_s_setprio(1);
      acc[0][0] = MFMA16(ah0, bh0, acc[0][0]);
      acc[0][0] = MFMA16(ah0, bl0, acc[0][0]);
      acc[0][0] = MFMA16(al0, bh0, acc[0][0]);
      acc[1][0] = MFMA16(ah1, bh0, acc[1][0]);
      acc[1][0] = MFMA16(ah1, bl0, acc[1][0]);
      acc[1][0] = MFMA16(al1, bh0, acc[1][0]);
      __builtin_amdgcn_s_setprio(0);
      __builtin_amdgcn_s_barrier();

      // ---- phase 1: B ni1 (A mp0 reused); stage A g1 ----
      bh1 = *(const f16x8*)(bt + offBr + 512);
      bl1 = *(const f16x8*)(bt + 8192 + offBr + 512);
      if (pre) stA(wb, nk0 + t, t, 1);
      __builtin_amdgcn_s_barrier();
      __builtin_amdgcn_s_setprio(1);
      acc[0][1] = MFMA16(ah0, bh1, acc[0][1]);
      acc[0][1] = MFMA16(ah0, bl1, acc[0][1]);
      acc[0][1] = MFMA16(al0, bh1, acc[0][1]);
      acc[1][1] = MFMA16(ah1, bh1, acc[1][1]);
      acc[1][1] = MFMA16(ah1, bl1, acc[1][1]);
      acc[1][1] = MFMA16(al1, bh1, acc[1][1]);
      __builtin_amdgcn_s_setprio(0);
      __builtin_amdgcn_s_barrier();

      // ---- phase 2: A mp1 (B ni1 reused); stage B h0 ----
      ah0 = *(const f16x8*)(at + offAr + 1024);
      ah1 = *(const f16x8*)(at + offAr + 1536);
      al0 = *(const f16x8*)(at + 4096 + offAr + 1024);
      al1 = *(const f16x8*)(at + 4096 + offAr + 1536);
      if (pre) stB(wb, nk0 + t, t, 0);
      __builtin_amdgcn_s_barrier();
      __builtin_amdgcn_s_setprio(1);
      acc[2][1] = MFMA16(ah0, bh1, acc[2][1]);
      acc[2][1] = MFMA16(ah0, bl1, acc[2][1]);
      acc[2][1] = MFMA16(al0, bh1, acc[2][1]);
      acc[3][1] = MFMA16(ah1, bh1, acc[3][1]);
      acc[3][1] = MFMA16(ah1, bl1, acc[3][1]);
      acc[3][1] = MFMA16(al1, bh1, acc[3][1]);
      __builtin_amdgcn_s_setprio(0);
      __builtin_amdgcn_s_barrier();

      // ---- phase 3: (A mp1, B ni0 reused); stage B h1 ----
      if (pre) stB(wb, nk0 + t, t, 1);
      __builtin_amdgcn_s_barrier();
      __builtin_amdgcn_s_setprio(1);
      acc[2][0] = MFMA16(ah0, bh0, acc[2][0]);
      acc[2][0] = MFMA16(ah0, bl0, acc[2][0]);
      acc[2][0] = MFMA16(al0, bh0, acc[2][0]);
      acc[3][0] = MFMA16(ah1, bh0, acc[3][0]);
      acc[3][0] = MFMA16(ah1, bl0, acc[3][0]);
      acc[3][0] = MFMA16(al1, bh0, acc[3][0]);
      __builtin_amdgcn_s_setprio(0);
      __builtin_amdgcn_s_barrier();
    }
  }

  // ---- epilogue: per-row argmax over this wave's 64 cols, merge across wn ----
  int c0 = nt * 256 + wn * 64 + lo5;
  int c1 = c0 + 32;
  float ch0 = ch[c0];
  float ch1 = ch[c1];
#pragma unroll
  for (int mi = 0; mi < 4; ++mi)
#pragma unroll
    for (int q = 0; q < 16; ++q) {
      float s0 = acc[mi][0][q] - ch0;
      float s1 = acc[mi][1][q] - ch1;
      float v = s0; int ix = c0;
      if (s1 > v) { v = s1; ix = c1; }   // c1 > c0: strict > keeps first index on ties
#pragma unroll
      for (int m = 1; m <= 16; m <<= 1) {
        float ov = __shfl_xor(v, m, 64);
        int   oi = __shfl_xor(ix, m, 64);
        if (ov > v || (ov == v && oi < ix)) { v = ov; ix = oi; }
      }
      if (lo5 == 0) {
        int rr = (q & 3) + ((q >> 2) << 3) + (p << 2);   // C/D row within 32x32 tile
        int rloc = wm * 128 + mi * 32 + rr;              // 0..255
        red_v[wn][rloc] = v;
        red_i[wn][rloc] = ix;
      }
    }
  __syncthreads();
  if (tid < 256) {
    float v = red_v[0][tid];
    int ix = red_i[0][tid];
#pragma unroll
    for (int w = 1; w < 4; ++w) {       // wn ascending => col ascending; strict > keeps first
      float ov = red_v[w][tid];
      int oi = red_i[w][tid];
      if (ov > v) { v = ov; ix = oi; }
    }
    int rowg = mt2 * 256 + tid;
    part[rowg * 4 + nt] = uint2{ __float_as_uint(v), (unsigned)ix };
  }
}

// ---------------- merge the 4 per-ntile candidates ----------------
__global__ void k_merge(const uint2* __restrict__ part, int* __restrict__ out) {
  int r = blockIdx.x * 256 + threadIdx.x;
  if (r >= MROWS) return;
  uint2 b0 = part[r * 4];
  float bvv = __uint_as_float(b0.x);
  int bii = (int)b0.y;
#pragma unroll
  for (int j = 1; j < 4; ++j) {
    uint2 pj = part[r * 4 + j];
    float v = __uint_as_float(pj.x);
    if (v > bvv) { bvv = v; bii = (int)pj.y; }   // nt ascending => idx ascending; strict >
  }
  out[r] = bii;
}

// ---------------- fallback (ws too small): fp32 wave-per-row ----------------
__global__ void k_naive(const float* __restrict__ E, const float* __restrict__ C,
                        int* __restrict__ out) {
  int row = blockIdx.x * 4 + (threadIdx.x >> 6);
  int lane = threadIdx.x & 63;
  const float* e = E + (size_t)row * KDIM;
  float bvv = -3.4e38f;
  int bii = 0;
  for (int c = 0; c < NCOLS; ++c) {
    const float* cc = C + (size_t)c * KDIM;
    float dot = 0.f, csq = 0.f;
    for (int d = lane; d < KDIM; d += 64) {
      float cv = cc[d];
      dot = fmaf(e[d], cv, dot);
      csq = fmaf(cv, cv, csq);
    }
#pragma unroll
    for (int m = 1; m < 64; m <<= 1) {
      dot += __shfl_xor(dot, m, 64);
      csq += __shfl_xor(csq, m, 64);
    }
    float s = dot - 0.5f * csq;
    if (s > bvv) { bvv = s; bii = c; }
  }
  if (lane == 0) out[row] = bii;
}

extern "C" void kernel_launch(void* const* d_in, const int* in_sizes, int n_in,
                              void* d_out, int out_size, void* d_ws, size_t ws_size,
                              hipStream_t stream) {
  const float* embed   = (const float*)d_in[0];
  const float* centers = (const float*)d_in[1];
  int* out = (int*)d_out;

  if (ws_size >= WS_NEED) {
    char* w = (char*)d_ws;
    _Float16* Aw = (_Float16*)w;
    _Float16* Bw = (_Float16*)(w + B_OFF);
    float*    ch = (float*)(w + CH_OFF);
    uint2*  partb = (uint2*)(w + PART_OFF);
    k_tile_A<<<188 * 48, 256, 0, stream>>>(embed, Aw);
    k_tile_B<<<4 * 48, 512, 0, stream>>>(centers, Bw);
    k_chalf<<<1024, 256, 0, stream>>>(centers, ch);
    k_gemm<<<376, 512, 0, stream>>>(Aw, Bw, ch, partb);
    k_merge<<<94, 256, 0, stream>>>(partb, out);
  } else {
    k_naive<<<6000, 256, 0, stream>>>(embed, centers, out);
  }
}

// Round 9
// 193.699 us; speedup vs baseline: 4.9293x; 1.1258x over previous
//
#include <hip/hip_runtime.h>
#include <cstdint>
#include <cstddef>

#define MROWS 24000
#define NCOLS 1024
#define KDIM  768
#define MT 188          // ceil(24000/128) m-tiles (padded to 24064 rows)
#define KT 48           // 768/16 k-tiles
#define NT 4            // 1024/256 n-tiles

typedef _Float16 f16x8  __attribute__((ext_vector_type(8)));
typedef float    f32x16 __attribute__((ext_vector_type(16)));

typedef __attribute__((address_space(1))) void as1_void;
typedef __attribute__((address_space(3))) void as3_void;

// ---- workspace layout (bytes) ----
#define A_BYTES   (188ull*48*8192)            // 73,924,608
#define B_OFF     A_BYTES
#define B_BYTES   (4ull*48*16384)             // 3,145,728
#define CH_OFF    (A_BYTES + B_BYTES)         // 77,070,336
#define PART_OFF  (CH_OFF + 4096)             // 77,074,432
#define WS_NEED   (PART_OFF + 24064ull*4*8)   // 77,844,480

// ---------------- conv A: embed -> tiled fp16 hi/lo ----------------
__global__ void k_tile_A(const float* __restrict__ E, _Float16* __restrict__ Aw) {
  int bid = blockIdx.x;            // mt*48 + kt
  int mt = bid / 48, kt = bid % 48;
  int t = threadIdx.x;             // 256
  int r = t >> 1, p = t & 1;
  int row = mt * 128 + r;
  __shared__ _Float16 lh[2][128][8];
  __shared__ _Float16 ll[2][128][8];
  float x[8];
  if (row < MROWS) {
    const float4* s4 = (const float4*)(E + (size_t)row * KDIM + kt * 16 + p * 8);
    float4 v0 = s4[0], v1 = s4[1];
    x[0]=v0.x; x[1]=v0.y; x[2]=v0.z; x[3]=v0.w; x[4]=v1.x; x[5]=v1.y; x[6]=v1.z; x[7]=v1.w;
  } else {
#pragma unroll
    for (int e = 0; e < 8; ++e) x[e] = 0.f;
  }
#pragma unroll
  for (int e = 0; e < 8; ++e) {
    _Float16 h = (_Float16)x[e];
    lh[p][r][e] = h;
    ll[p][r][e] = (_Float16)(x[e] - (float)h);
  }
  __syncthreads();
  const uint4* sh = (const uint4*)&lh[0][0][0];
  const uint4* sl = (const uint4*)&ll[0][0][0];
  uint4* dst = (uint4*)(Aw + (size_t)bid * 4096);   // 8192 B per tile
  dst[t]       = sh[t];    // h region: 256 chunks
  dst[256 + t] = sl[t];    // l region
}

// ---------------- conv B: centers -> tiled fp16 hi/lo ----------------
__global__ void k_tile_B(const float* __restrict__ C, _Float16* __restrict__ Bw) {
  int bid = blockIdx.x;            // nt*48 + kt
  int nt = bid / 48, kt = bid % 48;
  int t = threadIdx.x;             // 512
  int c = t >> 1, p = t & 1;
  __shared__ _Float16 lh[2][256][8];
  __shared__ _Float16 ll[2][256][8];
  const float4* s4 = (const float4*)(C + (size_t)(nt * 256 + c) * KDIM + kt * 16 + p * 8);
  float4 v0 = s4[0], v1 = s4[1];
  float x[8] = {v0.x, v0.y, v0.z, v0.w, v1.x, v1.y, v1.z, v1.w};
#pragma unroll
  for (int e = 0; e < 8; ++e) {
    _Float16 h = (_Float16)x[e];
    lh[p][c][e] = h;
    ll[p][c][e] = (_Float16)(x[e] - (float)h);
  }
  __syncthreads();
  const uint4* sh = (const uint4*)&lh[0][0][0];
  const uint4* sl = (const uint4*)&ll[0][0][0];
  uint4* dst = (uint4*)(Bw + (size_t)bid * 8192);   // 16384 B per tile
  dst[t]       = sh[t];    // h region: 512 chunks
  dst[512 + t] = sl[t];    // l region
}

// ---------------- 0.5*||c||^2 ----------------
__global__ void k_chalf(const float* __restrict__ C, float* __restrict__ ch) {
  int c = blockIdx.x, t = threadIdx.x;   // 256
  const float* src = C + (size_t)c * KDIM;
  float sq = 0.f;
#pragma unroll
  for (int i = 0; i < 3; ++i) {
    float x = src[t + i * 256];
    sq = fmaf(x, x, sq);
  }
#pragma unroll
  for (int m = 1; m < 64; m <<= 1) sq += __shfl_xor(sq, m, 64);
  __shared__ float part[4];
  if ((t & 63) == 0) part[t >> 6] = sq;
  __syncthreads();
  if (t == 0) ch[c] = 0.5f * ((part[0] + part[1]) + (part[2] + part[3]));
}

#define MFMA16(a, b, c) __builtin_amdgcn_mfma_f32_32x32x16_f16((a), (b), (c), 0, 0, 0)

// ---------------- fused GEMM: A via LDS ring-3 DMA, B global->reg ring-3 ----------------
// Diagnosis across R0-R8: global_load_lds sustains ~8 B/cyc/CU regardless of
// schedule; every variant staged >=24KB per K-step -> period ~6000cyc, MfmaUtil
// pinned ~26%. Fix: stage only A via DMA (8KB/K-step, 2 insts), load B to
// registers (the ~20 B/cyc path, L2-hot 786KB/XCD panel) prefetched ONE K-step
// ahead into a 3-deep named-set ring. Issue order per iter: ds_read A(j) ->
// loadB(j+1) -> stageA(j+2) -> MFMA. Entry wait vmcnt(2): in-order queue holds
// [B(j)x4, A(j+1)x2]; waiting-to-2 forces A(j)+B(j) landed, leaves A(j+1) in
// flight (fixes R3, whose B-after-A issue order drained the A-DMA every iter).
// 4 waves, wave tile 128x64, acc[4][2] (24 MFMA/wave-step, 2x R0's density).
// ~223 regs -> 2 waves/SIMD, 2 blocks/CU (R1: 2/SIMD loses nothing vs 4).
// Per-acc MFMA chain (hh, h*bl, al*bh; kt ascending) identical -> bitwise-
// identical scores to the verified baseline.
__global__ __launch_bounds__(256, 2) void k_gemm(
    const _Float16* __restrict__ Aw, const _Float16* __restrict__ Bw,
    const float* __restrict__ ch, uint2* __restrict__ part) {
  __shared__ __align__(16) char smem[3][8192];   // A ring: [hi 4K][lo 4K]
  // epilogue reduction arrays alias smem[0] (A-buf0 dead after K-loop)
  float (&red_v)[4][128] = *reinterpret_cast<float (*)[4][128]>(&smem[0][0]);
  int   (&red_i)[4][128] = *reinterpret_cast<int   (*)[4][128]>(&smem[0][2048]);

  const int bid0 = blockIdx.x;                    // 0..751
  const int swz = (bid0 & 7) * 94 + (bid0 >> 3);  // 752 = 8*94, bijective XCD swizzle
  const int nt = swz / MT, mt = swz % MT;

  const int tid = threadIdx.x, lane = tid & 63, wn = tid >> 6;  // 4 waves, 1x4 grid
  const int lo5 = lane & 31, p = lane >> 5;

  const char* Ab = (const char*)Aw + (size_t)mt * (48 * 8192);
  const char* Bb = (const char*)Bw + (size_t)nt * (48 * 16384);

  const int offA = p * 2048 + lo5 * 16;               // + mi*512; lo plane +4096
  const int offB = p * 4096 + (wn * 64 + lo5) * 16;   // + ni*512; lo plane +8192

  auto stageA = [&](char* sb, int kt) {   // 2 insts x 256thr x 16B = 8KB
    const char* ga = Ab + kt * 8192;
    __builtin_amdgcn_global_load_lds((as1_void*)(ga + tid * 16),
                                     (as3_void*)(sb + tid * 16), 16, 0, 0);
    __builtin_amdgcn_global_load_lds((as1_void*)(ga + 4096 + tid * 16),
                                     (as3_void*)(sb + 4096 + tid * 16), 16, 0, 0);
  };

  f32x16 acc[4][2] = {};

  // B register ring: 3 named sets (4 x f16x8 each)
  f16x8 b0h0, b0h1, b0l0, b0l1;
  f16x8 b1h0, b1h1, b1l0, b1l1;
  f16x8 b2h0, b2h1, b2l0, b2l1;

#define LOADB(S, kt)                                                          \
  do {                                                                        \
    const char* gb_ = Bb + (size_t)(kt) * 16384;                              \
    b##S##h0 = *(const f16x8*)(gb_ + offB);                                   \
    b##S##h1 = *(const f16x8*)(gb_ + offB + 512);                             \
    b##S##l0 = *(const f16x8*)(gb_ + 8192 + offB);                            \
    b##S##l1 = *(const f16x8*)(gb_ + 8192 + offB + 512);                      \
  } while (0)

  // one K-step: uses B set S (loaded last iter), A buf rb (staged 2 iters ago);
  // prefetches B set SN <- j+1, stages A wb <- j+2.
#define KSTEP(S, SN, rb, wb, j)                                               \
  do {                                                                        \
    if ((j) < KT - 1) asm volatile("s_waitcnt vmcnt(2)" ::: "memory");        \
    else              asm volatile("s_waitcnt vmcnt(0)" ::: "memory");        \
    __builtin_amdgcn_s_barrier();                                             \
    f16x8 ah0 = *(const f16x8*)((rb) + offA);                                 \
    f16x8 ah1 = *(const f16x8*)((rb) + offA + 512);                           \
    f16x8 ah2 = *(const f16x8*)((rb) + offA + 1024);                          \
    f16x8 ah3 = *(const f16x8*)((rb) + offA + 1536);                          \
    f16x8 al0 = *(const f16x8*)((rb) + 4096 + offA);                          \
    f16x8 al1 = *(const f16x8*)((rb) + 4096 + offA + 512);                    \
    f16x8 al2 = *(const f16x8*)((rb) + 4096 + offA + 1024);                   \
    f16x8 al3 = *(const f16x8*)((rb) + 4096 + offA + 1536);                   \
    if ((j) + 1 < KT) LOADB(SN, (j) + 1);                                     \
    if ((j) + 2 < KT) stageA((wb), (j) + 2);                                  \
    __builtin_amdgcn_s_setprio(1);                                            \
    acc[0][0] = MFMA16(ah0, b##S##h0, acc[0][0]);  /* per-acc: hh,hbl,albh */ \
    acc[0][0] = MFMA16(ah0, b##S##l0, acc[0][0]);                             \
    acc[0][0] = MFMA16(al0, b##S##h0, acc[0][0]);                             \
    acc[0][1] = MFMA16(ah0, b##S##h1, acc[0][1]);                             \
    acc[0][1] = MFMA16(ah0, b##S##l1, acc[0][1]);                             \
    acc[0][1] = MFMA16(al0, b##S##h1, acc[0][1]);                             \
    acc[1][0] = MFMA16(ah1, b##S##h0, acc[1][0]);                             \
    acc[1][0] = MFMA16(ah1, b##S##l0, acc[1][0]);                             \
    acc[1][0] = MFMA16(al1, b##S##h0, acc[1][0]);                             \
    acc[1][1] = MFMA16(ah1, b##S##h1, acc[1][1]);                             \
    acc[1][1] = MFMA16(ah1, b##S##l1, acc[1][1]);                             \
    acc[1][1] = MFMA16(al1, b##S##h1, acc[1][1]);                             \
    acc[2][0] = MFMA16(ah2, b##S##h0, acc[2][0]);                             \
    acc[2][0] = MFMA16(ah2, b##S##l0, acc[2][0]);                             \
    acc[2][0] = MFMA16(al2, b##S##h0, acc[2][0]);                             \
    acc[2][1] = MFMA16(ah2, b##S##h1, acc[2][1]);                             \
    acc[2][1] = MFMA16(ah2, b##S##l1, acc[2][1]);                             \
    acc[2][1] = MFMA16(al2, b##S##h1, acc[2][1]);                             \
    acc[3][0] = MFMA16(ah3, b##S##h0, acc[3][0]);                             \
    acc[3][0] = MFMA16(ah3, b##S##l0, acc[3][0]);                             \
    acc[3][0] = MFMA16(al3, b##S##h0, acc[3][0]);                             \
    acc[3][1] = MFMA16(ah3, b##S##h1, acc[3][1]);                             \
    acc[3][1] = MFMA16(ah3, b##S##l1, acc[3][1]);                             \
    acc[3][1] = MFMA16(al3, b##S##h1, acc[3][1]);                             \
    __builtin_amdgcn_s_setprio(0);                                            \
  } while (0)

  // prologue: B(0) first (so entry vmcnt(2) can retire it), then A(0), A(1)
  LOADB(0, 0);
  stageA(smem[0], 0);
  stageA(smem[1], 1);

#pragma unroll 1
  for (int jb = 0; jb < KT; jb += 3) {   // KT = 48, divisible by 3
    KSTEP(0, 1, smem[0], smem[2], jb);
    KSTEP(1, 2, smem[1], smem[0], jb + 1);
    KSTEP(2, 0, smem[2], smem[1], jb + 2);
  }

#undef KSTEP
#undef LOADB

  // ---- epilogue: per-row argmax over this wave's 64 cols, merge across wn ----
  // (all waves passed the final entry barrier; A-buf0 [aliased by red_*] was
  //  last read at j=45, safe to overwrite.)
  int c0 = nt * 256 + wn * 64 + lo5;
  int c1 = c0 + 32;
  float ch0 = ch[c0];
  float ch1 = ch[c1];
#pragma unroll
  for (int mi = 0; mi < 4; ++mi)
#pragma unroll
    for (int q = 0; q < 16; ++q) {
      float s0 = acc[mi][0][q] - ch0;
      float s1 = acc[mi][1][q] - ch1;
      float v = s0; int ix = c0;
      if (s1 > v) { v = s1; ix = c1; }   // c1 > c0: strict > keeps first index on ties
#pragma unroll
      for (int m = 1; m <= 16; m <<= 1) {
        float ov = __shfl_xor(v, m, 64);
        int   oi = __shfl_xor(ix, m, 64);
        if (ov > v || (ov == v && oi < ix)) { v = ov; ix = oi; }
      }
      if (lo5 == 0) {
        int rr = (q & 3) + ((q >> 2) << 3) + (p << 2);   // C/D row within 32x32 tile
        int rloc = mi * 32 + rr;                         // 0..127 (wave covers all rows)
        red_v[wn][rloc] = v;
        red_i[wn][rloc] = ix;
      }
    }
  __syncthreads();
  if (tid < 128) {
    float v = red_v[0][tid];
    int ix = red_i[0][tid];
#pragma unroll
    for (int w = 1; w < 4; ++w) {       // wn ascending => col ascending; strict > keeps first
      float ov = red_v[w][tid];
      int oi = red_i[w][tid];
      if (ov > v) { v = ov; ix = oi; }
    }
    int rowg = mt * 128 + tid;
    part[rowg * 4 + nt] = uint2{ __float_as_uint(v), (unsigned)ix };
  }
}

// ---------------- merge the 4 per-ntile candidates ----------------
__global__ void k_merge(const uint2* __restrict__ part, int* __restrict__ out) {
  int r = blockIdx.x * 256 + threadIdx.x;
  if (r >= MROWS) return;
  uint2 b0 = part[r * 4];
  float bvv = __uint_as_float(b0.x);
  int bii = (int)b0.y;
#pragma unroll
  for (int j = 1; j < 4; ++j) {
    uint2 pj = part[r * 4 + j];
    float v = __uint_as_float(pj.x);
    if (v > bvv) { bvv = v; bii = (int)pj.y; }   // nt ascending => idx ascending; strict >
  }
  out[r] = bii;
}

// ---------------- fallback (ws too small): fp32 wave-per-row ----------------
__global__ void k_naive(const float* __restrict__ E, const float* __restrict__ C,
                        int* __restrict__ out) {
  int row = blockIdx.x * 4 + (threadIdx.x >> 6);
  int lane = threadIdx.x & 63;
  const float* e = E + (size_t)row * KDIM;
  float bvv = -3.4e38f;
  int bii = 0;
  for (int c = 0; c < NCOLS; ++c) {
    const float* cc = C + (size_t)c * KDIM;
    float dot = 0.f, csq = 0.f;
    for (int d = lane; d < KDIM; d += 64) {
      float cv = cc[d];
      dot = fmaf(e[d], cv, dot);
      csq = fmaf(cv, cv, csq);
    }
#pragma unroll
    for (int m = 1; m < 64; m <<= 1) {
      dot += __shfl_xor(dot, m, 64);
      csq += __shfl_xor(csq, m, 64);
    }
    float s = dot - 0.5f * csq;
    if (s > bvv) { bvv = s; bii = c; }
  }
  if (lane == 0) out[row] = bii;
}

extern "C" void kernel_launch(void* const* d_in, const int* in_sizes, int n_in,
                              void* d_out, int out_size, void* d_ws, size_t ws_size,
                              hipStream_t stream) {
  const float* embed   = (const float*)d_in[0];
  const float* centers = (const float*)d_in[1];
  int* out = (int*)d_out;

  if (ws_size >= WS_NEED) {
    char* w = (char*)d_ws;
    _Float16* Aw = (_Float16*)w;
    _Float16* Bw = (_Float16*)(w + B_OFF);
    float*    ch = (float*)(w + CH_OFF);
    uint2*  partb = (uint2*)(w + PART_OFF);
    k_tile_A<<<188 * 48, 256, 0, stream>>>(embed, Aw);
    k_tile_B<<<4 * 48, 512, 0, stream>>>(centers, Bw);
    k_chalf<<<1024, 256, 0, stream>>>(centers, ch);
    k_gemm<<<752, 256, 0, stream>>>(Aw, Bw, ch, partb);
    k_merge<<<94, 256, 0, stream>>>(partb, out);
  } else {
    k_naive<<<6000, 256, 0, stream>>>(embed, centers, out);
  }
}

// Round 10
// 171.076 us; speedup vs baseline: 5.5812x; 1.1322x over previous
//
#include <hip/hip_runtime.h>
#include <cstdint>
#include <cstddef>

#define MROWS 24000
#define NCOLS 1024
#define KDIM  768
#define MT 188          // ceil(24000/128) m-tiles (padded to 24064 rows)
#define KT 48           // 768/16 k-tiles
#define NT 4            // 1024/256 n-tiles

typedef _Float16 f16x8  __attribute__((ext_vector_type(8)));
typedef float    f32x16 __attribute__((ext_vector_type(16)));

typedef __attribute__((address_space(1))) void as1_void;
typedef __attribute__((address_space(3))) void as3_void;

// ---- workspace layout (bytes) ----
#define A_BYTES   (188ull*48*8192)            // 73,924,608
#define B_OFF     A_BYTES
#define B_BYTES   (4ull*48*16384)             // 3,145,728
#define CH_OFF    (A_BYTES + B_BYTES)         // 77,070,336
#define PART_OFF  (CH_OFF + 4096)             // 77,074,432
#define WS_NEED   (PART_OFF + 24064ull*4*8)   // 77,844,480

// ---------------- conv A: embed -> tiled fp16 hi/lo ----------------
__global__ void k_tile_A(const float* __restrict__ E, _Float16* __restrict__ Aw) {
  int bid = blockIdx.x;            // mt*48 + kt
  int mt = bid / 48, kt = bid % 48;
  int t = threadIdx.x;             // 256
  int r = t >> 1, p = t & 1;
  int row = mt * 128 + r;
  __shared__ _Float16 lh[2][128][8];
  __shared__ _Float16 ll[2][128][8];
  float x[8];
  if (row < MROWS) {
    const float4* s4 = (const float4*)(E + (size_t)row * KDIM + kt * 16 + p * 8);
    float4 v0 = s4[0], v1 = s4[1];
    x[0]=v0.x; x[1]=v0.y; x[2]=v0.z; x[3]=v0.w; x[4]=v1.x; x[5]=v1.y; x[6]=v1.z; x[7]=v1.w;
  } else {
#pragma unroll
    for (int e = 0; e < 8; ++e) x[e] = 0.f;
  }
#pragma unroll
  for (int e = 0; e < 8; ++e) {
    _Float16 h = (_Float16)x[e];
    lh[p][r][e] = h;
    ll[p][r][e] = (_Float16)(x[e] - (float)h);
  }
  __syncthreads();
  const uint4* sh = (const uint4*)&lh[0][0][0];
  const uint4* sl = (const uint4*)&ll[0][0][0];
  uint4* dst = (uint4*)(Aw + (size_t)bid * 4096);   // 8192 B per tile
  dst[t]       = sh[t];    // h region: 256 chunks
  dst[256 + t] = sl[t];    // l region
}

// ---------------- conv B: centers -> tiled fp16 hi/lo ----------------
__global__ void k_tile_B(const float* __restrict__ C, _Float16* __restrict__ Bw) {
  int bid = blockIdx.x;            // nt*48 + kt
  int nt = bid / 48, kt = bid % 48;
  int t = threadIdx.x;             // 512
  int c = t >> 1, p = t & 1;
  __shared__ _Float16 lh[2][256][8];
  __shared__ _Float16 ll[2][256][8];
  const float4* s4 = (const float4*)(C + (size_t)(nt * 256 + c) * KDIM + kt * 16 + p * 8);
  float4 v0 = s4[0], v1 = s4[1];
  float x[8] = {v0.x, v0.y, v0.z, v0.w, v1.x, v1.y, v1.z, v1.w};
#pragma unroll
  for (int e = 0; e < 8; ++e) {
    _Float16 h = (_Float16)x[e];
    lh[p][c][e] = h;
    ll[p][c][e] = (_Float16)(x[e] - (float)h);
  }
  __syncthreads();
  const uint4* sh = (const uint4*)&lh[0][0][0];
  const uint4* sl = (const uint4*)&ll[0][0][0];
  uint4* dst = (uint4*)(Bw + (size_t)bid * 8192);   // 16384 B per tile
  dst[t]       = sh[t];    // h region: 512 chunks
  dst[512 + t] = sl[t];    // l region
}

// ---------------- 0.5*||c||^2 ----------------
__global__ void k_chalf(const float* __restrict__ C, float* __restrict__ ch) {
  int c = blockIdx.x, t = threadIdx.x;   // 256
  const float* src = C + (size_t)c * KDIM;
  float sq = 0.f;
#pragma unroll
  for (int i = 0; i < 3; ++i) {
    float x = src[t + i * 256];
    sq = fmaf(x, x, sq);
  }
#pragma unroll
  for (int m = 1; m < 64; m <<= 1) sq += __shfl_xor(sq, m, 64);
  __shared__ float part[4];
  if ((t & 63) == 0) part[t >> 6] = sq;
  __syncthreads();
  if (t == 0) ch[c] = 0.5f * ((part[0] + part[1]) + (part[2] + part[3]));
}

#define MFMA16(a, b, c) __builtin_amdgcn_mfma_f32_32x32x16_f16((a), (b), (c), 0, 0, 0)

// ---------------- fused GEMM: 8 waves, fine 2-phase/ktile, ring-3, counted vmcnt ----------------
// Best-verified variant of the session (R2: 170.1us, MfmaUtil 28.6). Block tile
// 128x256, 8 waves (2x4), wave tile 64x64, acc[2][2] 32x32 frags. Ring of 3 LDS
// buffers (24KB each): tile j in buf j%3; during ktile j we issue tile j+2's 3
// global_load_lds into the buffer freed at iter start. Entry barrier per ktile =
// s_waitcnt vmcnt(3); s_barrier -> tile j landed for all waves, tile j+1's 3
// loads stay in flight. Per phase: ds_reads -> stage issue -> barrier ->
// setprio(1) -> MFMA cluster -> setprio(0) -> barrier.
__global__ __launch_bounds__(512, 4) void k_gemm(
    const _Float16* __restrict__ Aw, const _Float16* __restrict__ Bw,
    const float* __restrict__ ch, uint2* __restrict__ part) {
  __shared__ __align__(16) char smem[3][24576];   // per buf: [A-h 4K][A-l 4K][B-h 8K][B-l 8K]
  __shared__ float red_v[4][128];
  __shared__ int   red_i[4][128];

  const int bid0 = blockIdx.x;                  // 0..751
  const int swz = (bid0 & 7) * 94 + (bid0 >> 3);  // 752 = 8*94, bijective XCD swizzle
  const int nt = swz / MT, mt = swz % MT;

  const int tid = threadIdx.x, lane = tid & 63, wid = tid >> 6;  // 8 waves
  const int wm = wid >> 2, wn = wid & 3;        // 2x4 wave grid, wave tile 64x64
  const int lo5 = lane & 31, p = lane >> 5;

  const char* Ab = (const char*)Aw + (size_t)mt * (48 * 8192);
  const char* Bb = (const char*)Bw + (size_t)nt * (48 * 16384);

  // one stage inst = 512 threads x 16B = 8KB
  auto stageA = [&](char* sb, int kt) {
    __builtin_amdgcn_global_load_lds((as1_void*)(Ab + kt * 8192 + tid * 16),
                                     (as3_void*)(sb + tid * 16), 16, 0, 0);
  };
  auto stageB0 = [&](char* sb, int kt) {
    __builtin_amdgcn_global_load_lds((as1_void*)(Bb + kt * 16384 + tid * 16),
                                     (as3_void*)(sb + 8192 + tid * 16), 16, 0, 0);
  };
  auto stageB1 = [&](char* sb, int kt) {
    __builtin_amdgcn_global_load_lds((as1_void*)(Bb + kt * 16384 + 8192 + tid * 16),
                                     (as3_void*)(sb + 16384 + tid * 16), 16, 0, 0);
  };

  f32x16 acc[2][2] = {};
  const int offA = p * 2048 + (wm * 64 + lo5) * 16;   // + mi*512
  const int offB = p * 4096 + (wn * 64 + lo5) * 16;   // + ni*512; lo plane at +8192

  char* rb = smem[0];   // tile j
  char* nb = smem[1];   // tile j+1 (in flight / landed)
  char* wb = smem[2];   // tile j+2 target

  stageA(smem[0], 0); stageB0(smem[0], 0); stageB1(smem[0], 0);
  stageA(smem[1], 1); stageB0(smem[1], 1); stageB1(smem[1], 1);

  for (int j = 0; j < KT; ++j) {
    // tile j landed (own 3 oldest); leave tile j+1's 3 in flight
    if (j < KT - 1) asm volatile("s_waitcnt vmcnt(3)" ::: "memory");
    else            asm volatile("s_waitcnt vmcnt(0)" ::: "memory");
    __builtin_amdgcn_s_barrier();

    // ---- phase 0: frags for ni=0 (+ all A); stage A + B0 of tile j+2 ----
    f16x8 ah0 = *(const f16x8*)(rb + offA);
    f16x8 ah1 = *(const f16x8*)(rb + offA + 512);
    f16x8 al0 = *(const f16x8*)(rb + 4096 + offA);
    f16x8 al1 = *(const f16x8*)(rb + 4096 + offA + 512);
    f16x8 bh0 = *(const f16x8*)(rb + 8192 + offB);
    f16x8 bl0 = *(const f16x8*)(rb + 16384 + offB);
    if (j + 2 < KT) { stageA(wb, j + 2); stageB0(wb, j + 2); }
    __builtin_amdgcn_s_barrier();
    __builtin_amdgcn_s_setprio(1);
    acc[0][0] = MFMA16(ah0, bh0, acc[0][0]);   // per-acc chain order: hh, h*bl, al*bh
    acc[0][0] = MFMA16(ah0, bl0, acc[0][0]);
    acc[0][0] = MFMA16(al0, bh0, acc[0][0]);
    acc[1][0] = MFMA16(ah1, bh0, acc[1][0]);
    acc[1][0] = MFMA16(ah1, bl0, acc[1][0]);
    acc[1][0] = MFMA16(al1, bh0, acc[1][0]);
    __builtin_amdgcn_s_setprio(0);
    __builtin_amdgcn_s_barrier();

    // ---- phase 1: frags for ni=1; stage B1 of tile j+2 ----
    f16x8 bh1 = *(const f16x8*)(rb + 8192 + offB + 512);
    f16x8 bl1 = *(const f16x8*)(rb + 16384 + offB + 512);
    if (j + 2 < KT) stageB1(wb, j + 2);
    __builtin_amdgcn_s_barrier();
    __builtin_amdgcn_s_setprio(1);
    acc[0][1] = MFMA16(ah0, bh1, acc[0][1]);
    acc[0][1] = MFMA16(ah0, bl1, acc[0][1]);
    acc[0][1] = MFMA16(al0, bh1, acc[0][1]);
    acc[1][1] = MFMA16(ah1, bh1, acc[1][1]);
    acc[1][1] = MFMA16(ah1, bl1, acc[1][1]);
    acc[1][1] = MFMA16(al1, bh1, acc[1][1]);
    __builtin_amdgcn_s_setprio(0);

    char* t = rb; rb = nb; nb = wb; wb = t;   // rotate ring
  }

  // ---- epilogue: per-row argmax over this wave's 64 cols, then merge across wn ----
  int c0 = nt * 256 + wn * 64 + lo5;
  int c1 = c0 + 32;
  float ch0 = ch[c0];
  float ch1 = ch[c1];
#pragma unroll
  for (int mi = 0; mi < 2; ++mi)
#pragma unroll
    for (int q = 0; q < 16; ++q) {
      float s0 = acc[mi][0][q] - ch0;
      float s1 = acc[mi][1][q] - ch1;
      float v = s0; int ix = c0;
      if (s1 > v) { v = s1; ix = c1; }   // c1 > c0: strict > keeps first index on ties
#pragma unroll
      for (int m = 1; m <= 16; m <<= 1) {
        float ov = __shfl_xor(v, m, 64);
        int   oi = __shfl_xor(ix, m, 64);
        if (ov > v || (ov == v && oi < ix)) { v = ov; ix = oi; }
      }
      if (lo5 == 0) {
        int rr = (q & 3) + ((q >> 2) << 3) + (p << 2);   // C/D row within 32x32 tile
        int rloc = wm * 64 + mi * 32 + rr;               // 0..127, unique per (wm,mi,q,p)
        red_v[wn][rloc] = v;
        red_i[wn][rloc] = ix;
      }
    }
  __syncthreads();
  if (tid < 128) {
    float v = red_v[0][tid];
    int ix = red_i[0][tid];
#pragma unroll
    for (int w = 1; w < 4; ++w) {       // wn ascending => col ascending; strict > keeps first
      float ov = red_v[w][tid];
      int oi = red_i[w][tid];
      if (ov > v) { v = ov; ix = oi; }
    }
    int rowg = mt * 128 + tid;
    part[rowg * 4 + nt] = uint2{ __float_as_uint(v), (unsigned)ix };
  }
}

// ---------------- merge the 4 per-ntile candidates ----------------
__global__ void k_merge(const uint2* __restrict__ part, int* __restrict__ out) {
  int r = blockIdx.x * 256 + threadIdx.x;
  if (r >= MROWS) return;
  uint2 b0 = part[r * 4];
  float bvv = __uint_as_float(b0.x);
  int bii = (int)b0.y;
#pragma unroll
  for (int j = 1; j < 4; ++j) {
    uint2 pj = part[r * 4 + j];
    float v = __uint_as_float(pj.x);
    if (v > bvv) { bvv = v; bii = (int)pj.y; }   // nt ascending => idx ascending; strict >
  }
  out[r] = bii;
}

// ---------------- fallback (ws too small): fp32 wave-per-row ----------------
__global__ void k_naive(const float* __restrict__ E, const float* __restrict__ C,
                        int* __restrict__ out) {
  int row = blockIdx.x * 4 + (threadIdx.x >> 6);
  int lane = threadIdx.x & 63;
  const float* e = E + (size_t)row * KDIM;
  float bvv = -3.4e38f;
  int bii = 0;
  for (int c = 0; c < NCOLS; ++c) {
    const float* cc = C + (size_t)c * KDIM;
    float dot = 0.f, csq = 0.f;
    for (int d = lane; d < KDIM; d += 64) {
      float cv = cc[d];
      dot = fmaf(e[d], cv, dot);
      csq = fmaf(cv, cv, csq);
    }
#pragma unroll
    for (int m = 1; m < 64; m <<= 1) {
      dot += __shfl_xor(dot, m, 64);
      csq += __shfl_xor(csq, m, 64);
    }
    float s = dot - 0.5f * csq;
    if (s > bvv) { bvv = s; bii = c; }
  }
  if (lane == 0) out[row] = bii;
}

extern "C" void kernel_launch(void* const* d_in, const int* in_sizes, int n_in,
                              void* d_out, int out_size, void* d_ws, size_t ws_size,
                              hipStream_t stream) {
  const float* embed   = (const float*)d_in[0];
  const float* centers = (const float*)d_in[1];
  int* out = (int*)d_out;

  if (ws_size >= WS_NEED) {
    char* w = (char*)d_ws;
    _Float16* Aw = (_Float16*)w;
    _Float16* Bw = (_Float16*)(w + B_OFF);
    float*    ch = (float*)(w + CH_OFF);
    uint2*  partb = (uint2*)(w + PART_OFF);
    k_tile_A<<<188 * 48, 256, 0, stream>>>(embed, Aw);
    k_tile_B<<<4 * 48, 512, 0, stream>>>(centers, Bw);
    k_chalf<<<1024, 256, 0, stream>>>(centers, ch);
    k_gemm<<<752, 512, 0, stream>>>(Aw, Bw, ch, partb);
    k_merge<<<94, 256, 0, stream>>>(partb, out);
  } else {
    k_naive<<<6000, 256, 0, stream>>>(embed, centers, out);
  }
}